// Round 2
// baseline (92.373 us; speedup 1.0000x reference)
//
#include <hip/hip_runtime.h>

#define T_STEPS 1024
#define B_ELEMS 32768
#define STEP 0.5f

typedef float f32x4 __attribute__((ext_vector_type(4)));

__global__ __launch_bounds__(64) void seir_euler_kernel(
    const float* __restrict__ initial,   // (4, B)
    const float* __restrict__ beta,
    const float* __restrict__ gamma,
    const float* __restrict__ sigma,
    f32x4* __restrict__ out,             // (T*B) rows of 4 floats
    int T, int B)
{
    int b = blockIdx.x * blockDim.x + threadIdx.x;
    if (b >= B) return;

    const float bb = beta[0];
    const float gg = gamma[0];
    const float ss = sigma[0];

    float S = initial[0 * B + b];
    float E = initial[1 * B + b];
    float I = initial[2 * B + b];
    float R = initial[3 * B + b];

    // Row 0 = initial state
    f32x4 v0 = {S, E, I, R};
    __builtin_nontemporal_store(v0, &out[b]);

    size_t idx = (size_t)B + b;
    for (int n = 1; n < T; ++n, idx += B) {
        float bSI = bb * S * I;
        float sE  = ss * E;
        float gI  = gg * I;
        float Sn = S - bSI * STEP;
        float En = E + (bSI - sE) * STEP;
        float In = I + (sE - gI) * STEP;
        float Rn = R + gI * STEP;
        S = Sn; E = En; I = In; R = Rn;
        f32x4 v = {S, E, I, R};
        __builtin_nontemporal_store(v, &out[idx]);
    }
}

extern "C" void kernel_launch(void* const* d_in, const int* in_sizes, int n_in,
                              void* d_out, int out_size, void* d_ws, size_t ws_size,
                              hipStream_t stream)
{
    const float* initial = (const float*)d_in[0];
    const float* beta    = (const float*)d_in[1];
    const float* gamma   = (const float*)d_in[2];
    const float* sigma   = (const float*)d_in[3];
    // d_in[4] is t (int scalar) — fixed at T_STEPS per problem definition.
    f32x4* out = (f32x4*)d_out;

    const int B = B_ELEMS;
    const int block = 64;               // spread 512 waves across all 256 CUs
    const int grid = (B + block - 1) / block;   // 512 blocks
    seir_euler_kernel<<<grid, block, 0, stream>>>(initial, beta, gamma, sigma,
                                                  out, T_STEPS, B);
}